// Round 20
// baseline (110.388 us; speedup 1.0000x reference)
//
#include <hip/hip_runtime.h>
#include <hip/hip_bf16.h>
#include <math.h>

#define N_TOTAL 8192
#define D_DIM   256
#define INV_T   10.0f
#define BM 128
#define BN 128
#define BKB 64                 // fp8 bytes (=elems) staged per round
#define ROUNDS (D_DIM / BKB)   // 4
#define NT 64                  // 8192/128 tiles per dim
#define N_TILES (NT * (NT + 1) / 2)   // 2080
#define NXCD 8
#define TPX (N_TILES / NXCD)   // 260 (2080 % 8 == 0, bijective)

typedef float f32x4 __attribute__((ext_vector_type(4)));

typedef const __attribute__((address_space(1))) unsigned int* gptr_t;
typedef __attribute__((address_space(3))) unsigned int*       lptr_t;

// async global->LDS, 16B per lane; LDS dest = wave-uniform base + lane*16 [m97/m104]
__device__ __forceinline__ void gload16(const void* g, void* l) {
    __builtin_amdgcn_global_load_lds((gptr_t)g, (lptr_t)l, 16, 0, 0);
}

// VALU-pipe 16-lane sum via DPP row_shr inclusive scan (verified correct, r13).
template <int CTRL>
__device__ __forceinline__ float dpp_add(float x) {
    int y = __builtin_amdgcn_update_dpp(0, __float_as_int(x), CTRL, 0xf, 0xf, true);
    return x + __int_as_float(y);
}
__device__ __forceinline__ float row16_sum(float x) {
    x = dpp_add<0x111>(x);   // row_shr:1
    x = dpp_add<0x112>(x);   // row_shr:2
    x = dpp_add<0x114>(x);   // row_shr:4
    x = dpp_add<0x118>(x);   // row_shr:8
    return x;                // valid in lane (cj==15) of each 16-lane group
}

// Kernel 1: L2-normalize concat(q,k) -> fp8 e4m3 F[8192][256]; zero out[0].
// HW cvt (v_cvt_pk_fp8_f32, RNE, native OCP e4m3fn on gfx950).
__global__ __launch_bounds__(256) void normalize_kernel(
    const float* __restrict__ q, const float* __restrict__ k,
    unsigned char* __restrict__ F, float* __restrict__ out)
{
    if (blockIdx.x == 0 && threadIdx.x == 0) out[0] = 0.f;
    int row  = blockIdx.x * 4 + (threadIdx.x >> 6);
    int lane = threadIdx.x & 63;
    const float* src = (row < 4096) ? (q + (size_t)row * D_DIM)
                                    : (k + (size_t)(row - 4096) * D_DIM);
    float4 v = ((const float4*)src)[lane];
    float ss = v.x*v.x + v.y*v.y + v.z*v.z + v.w*v.w;
    #pragma unroll
    for (int off = 32; off > 0; off >>= 1) ss += __shfl_xor(ss, off, 64);
    float inv = 1.0f / fmaxf(sqrtf(ss), 1e-12f);
    int p = 0;
    p = __builtin_amdgcn_cvt_pk_fp8_f32(v.x * inv, v.y * inv, p, false); // bytes 0-1
    p = __builtin_amdgcn_cvt_pk_fp8_f32(v.z * inv, v.w * inv, p, true);  // bytes 2-3
    ((unsigned int*)(F + (size_t)row * D_DIM))[lane] = (unsigned int)p;
}

__device__ __forceinline__ int tri_off(int x) { return x * NT - (x * (x - 1)) / 2; }

// Kernel 2: upper-triangular tiled F*F^T (fp8 e4m3) with fused exp epilogue.
// r20: fp8 halves every staged byte: 1024 L2 lines/block (was 2048), 16
// staging gloads/wave (was 32), ds_read_b64 frags (was b128), F = 2MB
// (L2-resident per XCD). MFMA fp8 16x16x32 = bf16 rate; C/D layout is
// dtype-independent -> epilogue unchanged (DPP esum r14, specialization r18,
// launch_bounds(256,4) r17, XCD swizzle r19).
// Staging: 4 lanes/row over the row's 64B k-slab -> fully-used 64B lines
// (r8 discipline). 4 rounds x {barrier; stage-next; vmcnt(4); 2 MFMA steps}.
// NO global S atomics: partial[t][r] has exactly one writer block (r2 proof).
__global__ __launch_bounds__(256, 4) void simloss_gemm(
    const unsigned char* __restrict__ F,
    float* __restrict__ partial, float* __restrict__ pos)
{
    __shared__ __align__(16) unsigned char As[2][BM * BKB];   // 2 x 8 KB
    __shared__ __align__(16) unsigned char Bs[2][BN * BKB];   // 2 x 8 KB
    __shared__ float s_row[BM];
    __shared__ float s_col[BN];

    // XCD swizzle (r19): contiguous 260-tile run per XCD. Bijective.
    const int wg = blockIdx.x;
    int b = (wg & (NXCD - 1)) * TPX + (wg >> 3);

    // invert linear tile id -> (bx, by), bx <= by
    int bx = (int)(64.5f - sqrtf(64.5f * 64.5f - 2.0f * (float)b));
    if (bx < 0) bx = 0; if (bx > NT - 1) bx = NT - 1;
    while (bx > 0 && tri_off(bx) > b) --bx;
    while (bx < NT - 1 && tri_off(bx + 1) <= b) ++bx;
    const int by = bx + (b - tri_off(bx));
    const bool is_diag = (bx == by);
    const bool general = is_diag || (by == bx + 32);   // diag or positive-carrying

    const int i0 = bx * BM;
    const int j0 = by * BN;
    const int tid  = threadIdx.x;
    const int wave = tid >> 6;
    const int lane = tid & 63;
    const int wm = (wave & 1) * 64;
    const int wn = (wave >> 1) * 64;
    const int g  = lane >> 4;
    const int cj = lane & 15;
    const int srow  = lane >> 2;         // staging: row within 16-row group
    const int squar = (lane & 3) * 16;   // staging: 16B quarter of 64B slab

    if (tid < BM) { s_row[tid] = 0.f; s_col[tid] = 0.f; }   // sealed by t=0 barrier

    f32x4 acc[4][4];
    #pragma unroll
    for (int a = 0; a < 4; ++a)
        #pragma unroll
        for (int c = 0; c < 4; ++c)
            acc[a][c] = (f32x4){0.f, 0.f, 0.f, 0.f};

    // Wave w stages rows w*32..w*32+31 of A and B for one 64B k-slab;
    // 4 lanes/row, fully coalesced 64B lines; 4 gloads/wave/round.
    #define STAGE(buf, t)                                                              \
        _Pragma("unroll")                                                              \
        for (int p = 0; p < 2; ++p) {                                                  \
            gload16(F + (size_t)(i0 + wave * 32 + p * 16 + srow) * D_DIM + (t) * BKB + squar, \
                    &As[buf][(wave * 32 + p * 16) * BKB]);                             \
            gload16(F + (size_t)(j0 + wave * 32 + p * 16 + srow) * D_DIM + (t) * BKB + squar, \
                    &Bs[buf][(wave * 32 + p * 16) * BKB]);                             \
        }

    STAGE(0, 0);
    int cur = 0;
    #pragma unroll
    for (int t = 0; t < ROUNDS; ++t) {
        // Collective barrier: buf[cur^1] (staged below) was consumed at t-1.
        __builtin_amdgcn_s_barrier();
        if (t + 1 < ROUNDS) {
            STAGE(cur ^ 1, t + 1);
            // wait for buf[cur]'s 4 loads; the 4 just issued stay in flight.
            asm volatile("s_waitcnt vmcnt(4)" ::: "memory");
        } else {
            asm volatile("s_waitcnt vmcnt(0)" ::: "memory");
        }

        #pragma unroll
        for (int s = 0; s < 2; ++s) {     // two K=32 MFMA steps per 64B slab
            long a[4], bq[4];
            #pragma unroll
            for (int u = 0; u < 4; ++u) {
                a[u]  = *(const long*)(&As[cur][(wm + u * 16 + cj) * BKB + s * 32 + g * 8]);
                bq[u] = *(const long*)(&Bs[cur][(wn + u * 16 + cj) * BKB + s * 32 + g * 8]);
            }
            #pragma unroll
            for (int ti = 0; ti < 4; ++ti)
                #pragma unroll
                for (int tj = 0; tj < 4; ++tj)
                    acc[ti][tj] = __builtin_amdgcn_mfma_f32_16x16x32_fp8_fp8(
                        a[ti], bq[tj], acc[ti][tj], 0, 0, 0);
        }
        cur ^= 1;
    }
    #undef STAGE

    // Epilogue. C/D layout: col = lane&15, row = (lane>>4)*4 + reg [m89/m91]
    float colsum[4] = {0.f, 0.f, 0.f, 0.f};
    if (general) {
        #pragma unroll
        for (int ti = 0; ti < 4; ++ti) {
            #pragma unroll
            for (int r = 0; r < 4; ++r) {
                const int i = i0 + wm + ti * 16 + g * 4 + r;
                const int partner = (i + 4096) & (N_TOTAL - 1);
                float esum = 0.f;
                #pragma unroll
                for (int tj = 0; tj < 4; ++tj) {
                    const int j = j0 + wn + tj * 16 + cj;
                    const float v = acc[ti][tj][r];
                    float e = __expf(v * INV_T);
                    if (is_diag && j == i) e = 0.f;               // exclude diagonal
                    if (!is_diag && j == partner) {               // mutual positives
                        pos[i] = v; pos[j] = v;
                    }
                    esum += e;
                    colsum[tj] += e;
                }
                esum = row16_sum(esum);                           // DPP, VALU pipe
                if (cj == 15) atomicAdd(&s_row[wm + ti * 16 + g * 4 + r], esum);
            }
        }
    } else {
        #pragma unroll
        for (int ti = 0; ti < 4; ++ti) {
            #pragma unroll
            for (int r = 0; r < 4; ++r) {
                float esum = 0.f;
                #pragma unroll
                for (int tj = 0; tj < 4; ++tj) {
                    float e = __expf(acc[ti][tj][r] * INV_T);
                    esum += e;
                    colsum[tj] += e;
                }
                esum = row16_sum(esum);                           // DPP, VALU pipe
                if (cj == 15) atomicAdd(&s_row[wm + ti * 16 + g * 4 + r], esum);
            }
        }
    }
    if (!is_diag) {
        #pragma unroll
        for (int tj = 0; tj < 4; ++tj) {
            float cs = colsum[tj];
            cs += __shfl_xor(cs, 16, 64);
            cs += __shfl_xor(cs, 32, 64);
            if (g == 0) atomicAdd(&s_col[wn + tj * 16 + cj], cs);          // LDS
        }
    }
    __syncthreads();

    // Unique-owner partial stores (coalesced 512B per half-block).
    if (tid < BM) {
        partial[(size_t)by * N_TOTAL + i0 + tid] = s_row[tid];
    } else if (!is_diag) {
        partial[(size_t)bx * N_TOTAL + j0 + (tid - BM)] = s_col[tid - BM];
    }
}

// Kernel 3: S_i = sum_t partial[t][i]; loss = mean_i( log(S_i) - 10*pos_i ).
__global__ __launch_bounds__(256) void finalize_kernel(
    const float* __restrict__ partial, const float* __restrict__ pos,
    float* __restrict__ out)
{
    const int row = blockIdx.x * 256 + threadIdx.x;
    float s = 0.f;
    #pragma unroll 8
    for (int t = 0; t < NT; ++t)
        s += partial[(size_t)t * N_TOTAL + row];
    float v = logf(s) - pos[row] * INV_T;
    #pragma unroll
    for (int off = 32; off > 0; off >>= 1) v += __shfl_xor(v, off, 64);
    __shared__ float wsum[4];
    if ((threadIdx.x & 63) == 0) wsum[threadIdx.x >> 6] = v;
    __syncthreads();
    if (threadIdx.x == 0)
        atomicAdd(out, (wsum[0] + wsum[1] + wsum[2] + wsum[3]) * (1.0f / N_TOTAL));
}

extern "C" void kernel_launch(void* const* d_in, const int* in_sizes, int n_in,
                              void* d_out, int out_size, void* d_ws, size_t ws_size,
                              hipStream_t stream) {
    const float* q = (const float*)d_in[0];
    const float* k = (const float*)d_in[1];
    float* out = (float*)d_out;

    char* ws = (char*)d_ws;
    const size_t f_bytes = (size_t)N_TOTAL * D_DIM;                          // 2 MB fp8
    const size_t p_bytes = (size_t)NT * N_TOTAL * sizeof(float);             // 2 MB
    unsigned char* F = (unsigned char*)ws;
    float* partial = (float*)(ws + f_bytes);
    float* pos     = (float*)(ws + f_bytes + p_bytes);

    normalize_kernel<<<N_TOTAL / 4, 256, 0, stream>>>(q, k, F, out);
    simloss_gemm<<<N_TILES, 256, 0, stream>>>(F, partial, pos);
    finalize_kernel<<<32, 256, 0, stream>>>(partial, pos, out);
}

// Round 21
// 95.799 us; speedup vs baseline: 1.1523x; 1.1523x over previous
//
#include <hip/hip_runtime.h>
#include <hip/hip_bf16.h>
#include <math.h>

#define N_TOTAL 8192
#define D_DIM   256
#define INV_T   10.0f
#define BM 128
#define BN 128
#define BK 32
#define K_ITERS (D_DIM / BK)   // 8
#define NT 64                  // 8192/128 tiles per dim
#define N_TILES (NT * (NT + 1) / 2)   // 2080
#define NXCD 8
#define TPX (N_TILES / NXCD)   // 260 tiles per XCD (2080 % 8 == 0, bijective)

typedef __bf16 bf16_8 __attribute__((ext_vector_type(8)));
typedef float  f32x4  __attribute__((ext_vector_type(4)));

typedef const __attribute__((address_space(1))) unsigned int* gptr_t;
typedef __attribute__((address_space(3))) unsigned int*       lptr_t;

// async global->LDS, 16B per lane; LDS dest = wave-uniform base + lane*16 [m97/m104]
__device__ __forceinline__ void gload16(const void* g, void* l) {
    __builtin_amdgcn_global_load_lds((gptr_t)g, (lptr_t)l, 16, 0, 0);
}

__device__ __forceinline__ unsigned short f2bf(float f) {
    unsigned int u = __float_as_uint(f);
    return (unsigned short)((u + 0x7FFFu + ((u >> 16) & 1u)) >> 16);
}

// VALU-pipe 16-lane sum via DPP row_shr inclusive scan (verified correct, r13).
template <int CTRL>
__device__ __forceinline__ float dpp_add(float x) {
    int y = __builtin_amdgcn_update_dpp(0, __float_as_int(x), CTRL, 0xf, 0xf, true);
    return x + __int_as_float(y);
}
__device__ __forceinline__ float row16_sum(float x) {
    x = dpp_add<0x111>(x);   // row_shr:1
    x = dpp_add<0x112>(x);   // row_shr:2
    x = dpp_add<0x114>(x);   // row_shr:4
    x = dpp_add<0x118>(x);   // row_shr:8
    return x;                // valid in lane (cj==15) of each 16-lane group
}

// Kernel 1: L2-normalize concat(q,k) -> bf16 F[8192][256]; also zero out[0].
__global__ __launch_bounds__(256) void normalize_kernel(
    const float* __restrict__ q, const float* __restrict__ k,
    unsigned short* __restrict__ F, float* __restrict__ out)
{
    if (blockIdx.x == 0 && threadIdx.x == 0) out[0] = 0.f;
    int row  = blockIdx.x * 4 + (threadIdx.x >> 6);
    int lane = threadIdx.x & 63;
    const float* src = (row < 4096) ? (q + (size_t)row * D_DIM)
                                    : (k + (size_t)(row - 4096) * D_DIM);
    float4 v = ((const float4*)src)[lane];
    float ss = v.x*v.x + v.y*v.y + v.z*v.z + v.w*v.w;
    #pragma unroll
    for (int off = 32; off > 0; off >>= 1) ss += __shfl_xor(ss, off, 64);
    float inv = 1.0f / fmaxf(sqrtf(ss), 1e-12f);
    ushort4 o;
    o.x = f2bf(v.x * inv); o.y = f2bf(v.y * inv);
    o.z = f2bf(v.z * inv); o.w = f2bf(v.w * inv);
    ((ushort4*)(F + (size_t)row * D_DIM))[lane] = o;
}

__device__ __forceinline__ int tri_off(int x) { return x * NT - (x * (x - 1)) / 2; }

// Kernel 2: upper-triangular tiled F*F^T with fused exp epilogue.
// Structure = accumulated wins only:
//   r2: no-global-atomic unique-owner partials; r8: identity-order coalesced
//   4-lanes/row staging (TA-rate fix); r11/r14: single-barrier dbuf, counted
//   vmcnt; r14: DPP esum (VALU pipe); r17: launch_bounds(256,4) -> 4 blk/CU;
//   r18: block-uniform epilogue specialization; r19: XCD tile swizzle.
// r20's fp8 REVERTED: 8-way LDS conflicts on 8B frags (1.49e7 cyc) ate the
// byte savings -- staging granule (16B) vs fragment granule (8B) vs linear
// LDS dest [m104] are jointly unsatisfiable conflict-free.
__global__ __launch_bounds__(256, 4) void simloss_gemm(
    const __hip_bfloat16* __restrict__ F,
    float* __restrict__ partial, float* __restrict__ pos)
{
    __shared__ __hip_bfloat16 As[2][BM * BK];   // 2 x 8 KB, row-major [128][32]
    __shared__ __hip_bfloat16 Bs[2][BN * BK];   // 2 x 8 KB
    __shared__ float s_row[BM];
    __shared__ float s_col[BN];

    // XCD swizzle: contiguous 260-tile run per XCD. Bijective (2080 = 8*260).
    const int wg = blockIdx.x;
    int b = (wg & (NXCD - 1)) * TPX + (wg >> 3);

    // invert linear tile id -> (bx, by), bx <= by
    int bx = (int)(64.5f - sqrtf(64.5f * 64.5f - 2.0f * (float)b));
    if (bx < 0) bx = 0; if (bx > NT - 1) bx = NT - 1;
    while (bx > 0 && tri_off(bx) > b) --bx;
    while (bx < NT - 1 && tri_off(bx + 1) <= b) ++bx;
    const int by = bx + (b - tri_off(bx));
    const bool is_diag = (bx == by);
    const bool general = is_diag || (by == bx + 32);   // diag or positive-carrying

    const int i0 = bx * BM;
    const int j0 = by * BN;
    const int tid  = threadIdx.x;
    const int wave = tid >> 6;
    const int lane = tid & 63;
    const int wm = (wave & 1) * 64;
    const int wn = (wave >> 1) * 64;
    const int g  = lane >> 4;
    const int cj = lane & 15;
    const int srow  = lane >> 2;        // staging: row within 16-row group
    const int squar = (lane & 3) * 8;   // staging: 16B quarter, identity order

    if (tid < BM) { s_row[tid] = 0.f; s_col[tid] = 0.f; }   // sealed by k=0 barrier

    f32x4 acc[4][4];
    #pragma unroll
    for (int a = 0; a < 4; ++a)
        #pragma unroll
        for (int c = 0; c < 4; ++c)
            acc[a][c] = (f32x4){0.f, 0.f, 0.f, 0.f};

    // Wave w stages rows w*32..w*32+31 of A and B; 4 lanes/row, fully
    // coalesced 64B lines; 4 gloads/wave/iter.
    #define STAGE(buf, kk)                                                            \
        _Pragma("unroll")                                                             \
        for (int p = 0; p < 2; ++p) {                                                 \
            gload16(F + (size_t)(i0 + wave * 32 + p * 16 + srow) * D_DIM + (kk) + squar, \
                    &As[buf][(wave * 32 + p * 16) * BK]);                             \
            gload16(F + (size_t)(j0 + wave * 32 + p * 16 + srow) * D_DIM + (kk) + squar, \
                    &Bs[buf][(wave * 32 + p * 16) * BK]);                             \
        }

    STAGE(0, 0);
    int cur = 0;
    for (int kk = 0; kk < K_ITERS; ++kk) {
        // Collective barrier: all waves consumed buf[cur^1] (read at iter kk-1),
        // so staging into it below is safe. Also seals s_row/s_col init at kk=0.
        __builtin_amdgcn_s_barrier();
        if (kk + 1 < K_ITERS) {
            STAGE(cur ^ 1, (kk + 1) * BK);
            // wait for buf[cur]'s 4 loads; the 4 just issued stay in flight.
            asm volatile("s_waitcnt vmcnt(4)" ::: "memory");
        } else {
            asm volatile("s_waitcnt vmcnt(0)" ::: "memory");
        }

        bf16_8 a[4], bfr[4];
        #pragma unroll
        for (int t = 0; t < 4; ++t) {
            a[t]   = *(const bf16_8*)(&As[cur][(wm + t * 16 + cj) * BK + g * 8]);
            bfr[t] = *(const bf16_8*)(&Bs[cur][(wn + t * 16 + cj) * BK + g * 8]);
        }
        #pragma unroll
        for (int ti = 0; ti < 4; ++ti)
            #pragma unroll
            for (int tj = 0; tj < 4; ++tj)
                acc[ti][tj] = __builtin_amdgcn_mfma_f32_16x16x32_bf16(
                    a[ti], bfr[tj], acc[ti][tj], 0, 0, 0);

        cur ^= 1;
    }
    #undef STAGE

    // Epilogue. C/D layout: col = lane&15, row = (lane>>4)*4 + reg [m89/m91]
    float colsum[4] = {0.f, 0.f, 0.f, 0.f};
    if (general) {
        // 96 blocks: diagonal exclusion and/or positive extraction needed.
        #pragma unroll
        for (int ti = 0; ti < 4; ++ti) {
            #pragma unroll
            for (int r = 0; r < 4; ++r) {
                const int i = i0 + wm + ti * 16 + g * 4 + r;
                const int partner = (i + 4096) & (N_TOTAL - 1);
                float esum = 0.f;
                #pragma unroll
                for (int tj = 0; tj < 4; ++tj) {
                    const int j = j0 + wn + tj * 16 + cj;
                    const float v = acc[ti][tj][r];
                    float e = __expf(v * INV_T);
                    if (is_diag && j == i) e = 0.f;               // exclude diagonal
                    if (!is_diag && j == partner) {               // mutual positives
                        pos[i] = v; pos[j] = v;
                    }
                    esum += e;
                    colsum[tj] += e;
                }
                esum = row16_sum(esum);                           // DPP, VALU pipe
                if (cj == 15) atomicAdd(&s_row[wm + ti * 16 + g * 4 + r], esum);
            }
        }
    } else {
        // 1984 blocks: pure accumulate -- no compares, no dead pos stores.
        #pragma unroll
        for (int ti = 0; ti < 4; ++ti) {
            #pragma unroll
            for (int r = 0; r < 4; ++r) {
                float esum = 0.f;
                #pragma unroll
                for (int tj = 0; tj < 4; ++tj) {
                    float e = __expf(acc[ti][tj][r] * INV_T);
                    esum += e;
                    colsum[tj] += e;
                }
                esum = row16_sum(esum);                           // DPP, VALU pipe
                if (cj == 15) atomicAdd(&s_row[wm + ti * 16 + g * 4 + r], esum);
            }
        }
    }
    if (!is_diag) {
        #pragma unroll
        for (int tj = 0; tj < 4; ++tj) {
            float cs = colsum[tj];
            cs += __shfl_xor(cs, 16, 64);
            cs += __shfl_xor(cs, 32, 64);
            if (g == 0) atomicAdd(&s_col[wn + tj * 16 + cj], cs);          // LDS
        }
    }
    __syncthreads();

    // Unique-owner partial stores (coalesced 512B per half-block).
    if (tid < BM) {
        partial[(size_t)by * N_TOTAL + i0 + tid] = s_row[tid];
    } else if (!is_diag) {
        partial[(size_t)bx * N_TOTAL + j0 + (tid - BM)] = s_col[tid - BM];
    }
}

// Kernel 3: S_i = sum_t partial[t][i]; loss = mean_i( log(S_i) - 10*pos_i ).
__global__ __launch_bounds__(256) void finalize_kernel(
    const float* __restrict__ partial, const float* __restrict__ pos,
    float* __restrict__ out)
{
    const int row = blockIdx.x * 256 + threadIdx.x;
    float s = 0.f;
    #pragma unroll 8
    for (int t = 0; t < NT; ++t)
        s += partial[(size_t)t * N_TOTAL + row];
    float v = logf(s) - pos[row] * INV_T;
    #pragma unroll
    for (int off = 32; off > 0; off >>= 1) v += __shfl_xor(v, off, 64);
    __shared__ float wsum[4];
    if ((threadIdx.x & 63) == 0) wsum[threadIdx.x >> 6] = v;
    __syncthreads();
    if (threadIdx.x == 0)
        atomicAdd(out, (wsum[0] + wsum[1] + wsum[2] + wsum[3]) * (1.0f / N_TOTAL));
}

extern "C" void kernel_launch(void* const* d_in, const int* in_sizes, int n_in,
                              void* d_out, int out_size, void* d_ws, size_t ws_size,
                              hipStream_t stream) {
    const float* q = (const float*)d_in[0];
    const float* k = (const float*)d_in[1];
    float* out = (float*)d_out;

    char* ws = (char*)d_ws;
    const size_t f_bytes = (size_t)N_TOTAL * D_DIM * sizeof(unsigned short); // 4 MB
    const size_t p_bytes = (size_t)NT * N_TOTAL * sizeof(float);             // 2 MB
    unsigned short* F = (unsigned short*)ws;
    float* partial = (float*)(ws + f_bytes);
    float* pos     = (float*)(ws + f_bytes + p_bytes);

    normalize_kernel<<<N_TOTAL / 4, 256, 0, stream>>>(q, k, F, out);
    simloss_gemm<<<N_TILES, 256, 0, stream>>>((const __hip_bfloat16*)F, partial, pos);
    finalize_kernel<<<32, 256, 0, stream>>>(partial, pos, out);
}